// Round 13
// baseline (160.419 us; speedup 1.0000x reference)
//
#include <hip/hip_runtime.h>
#include <hip/hip_bf16.h>

typedef __bf16 bf16;
typedef __bf16 bf16x8 __attribute__((ext_vector_type(8)));
typedef __bf16 bf16x4 __attribute__((ext_vector_type(4)));
typedef float f32x4 __attribute__((ext_vector_type(4)));

static __device__ __forceinline__ f32x4 mfma16(bf16x8 a, bf16x8 b, f32x4 c) {
  return __builtin_amdgcn_mfma_f32_16x16x32_bf16(a, b, c, 0, 0, 0);
}

// No-drain workgroup barrier: waits only LDS ops, leaves global loads in
// flight (r5-proven correct).
static __device__ __forceinline__ void wg_barrier() {
  asm volatile("s_waitcnt lgkmcnt(0)" ::: "memory");
  __builtin_amdgcn_s_barrier();
  asm volatile("" ::: "memory");
}

static __device__ __forceinline__ bf16x8 cvt8(const float* p) {
  f32x4 a0 = *(const f32x4*)p;
  f32x4 a1 = *(const f32x4*)(p + 4);
  bf16x8 r;
#pragma unroll
  for (int j = 0; j < 4; ++j) { r[j] = (bf16)a0[j]; r[4 + j] = (bf16)a1[j]; }
  return r;
}

// ---------------------------------------------------------------------------
// prep_wt: W in MFMA B-fragment order (unchanged, proven).
// ---------------------------------------------------------------------------
__global__ void prep_wt(const float* __restrict__ Wq, const float* __restrict__ Wk,
                        const float* __restrict__ Wv, bf16* __restrict__ Wf) {
  int k = blockIdx.x;   // 0..255
  int c = threadIdx.x;  // 0..319
  float v;
  if (c < 32)       v = Wq[k * 32 + c];
  else if (c < 64)  v = Wk[k * 32 + (c - 32)];
  else              v = Wv[k * 256 + (c - 64)];
  int t5 = c >> 6, ct = (c >> 4) & 3, lwc = c & 15;
  int kc = k >> 5, qq = (k >> 3) & 3, ke = k & 7;
  Wf[((((t5 * 8 + kc) * 4 + ct) * 64) + qq * 16 + lwc) * 8 + ke] = (bf16)v;
}

// ---------------------------------------------------------------------------
// qkv_gemm: r5-proven version (unchanged).
// ---------------------------------------------------------------------------
__global__ __launch_bounds__(256) void qkv_gemm(
    const float* __restrict__ x, const bf16* __restrict__ Wf,
    const float* __restrict__ bq, const float* __restrict__ bk,
    const float* __restrict__ bv,
    bf16* __restrict__ Qd, bf16* __restrict__ Kd, bf16* __restrict__ Vt) {
  __shared__ __align__(16) bf16 tile[64 * 72];
  int tid = threadIdx.x;
  int lane = tid & 63, w = tid >> 6;
  int lw = lane & 15, qq = lane >> 4;
  int r0 = blockIdx.x * 64;
  int bb = r0 >> 12, n0 = r0 & 4095;

  const float* arow = x + (size_t)(r0 + 16 * w + lw) * 256;
  bf16x8 a[8];
#pragma unroll
  for (int kc = 0; kc < 8; ++kc) a[kc] = cvt8(arow + kc * 32 + qq * 8);

  for (int c0 = 0; c0 < 320; c0 += 64) {
    int t5 = c0 >> 6;
    f32x4 acc[4] = {};
#pragma unroll
    for (int kc = 0; kc < 8; ++kc)
#pragma unroll
      for (int t = 0; t < 4; ++t) {
        bf16x8 b = *(const bf16x8*)(Wf + ((size_t)(((t5 * 8 + kc) * 4 + t) * 64) + lane) * 8);
        acc[t] = mfma16(a[kc], b, acc[t]);
      }
    if (c0 == 0) {
#pragma unroll
      for (int t = 0; t < 4; ++t) {
        int c = 16 * t + lw;
        float bias = (c < 32) ? bq[c] : bk[c - 32];
#pragma unroll
        for (int i = 0; i < 4; ++i) {
          int n = n0 + 16 * w + 4 * qq + i;
          bf16 hv = (bf16)(acc[t][i] + bias);
          if (c < 32) Qd[((size_t)(bb << 12) + n) * 32 + c] = hv;
          else        Kd[((size_t)(bb << 12) + n) * 32 + (c - 32)] = hv;
        }
      }
    } else {
#pragma unroll
      for (int t = 0; t < 4; ++t) {
        int cl = 16 * t + lw;
        float bias = bv[c0 - 64 + cl];
#pragma unroll
        for (int i = 0; i < 4; ++i)
          tile[cl * 72 + 16 * w + 4 * qq + i] = (bf16)(acc[t][i] + bias);
      }
      __syncthreads();
      int nl = tid & 63;
#pragma unroll
      for (int it = 0; it < 16; ++it) {
        int cl = 4 * it + w;
        Vt[((size_t)bb * 256 + (c0 - 64) + cl) * 4096 + n0 + nl] = tile[cl * 72 + nl];
      }
      __syncthreads();
    }
  }
}

// ---------------------------------------------------------------------------
// flash_attn v13 — producer/consumer (r12-proven, −12%) + SUPER-PHASES:
// one barrier per 2 KV-tiles (33 barriers vs 66). r12's residual was
// ~2000 cyc/phase of fixed cost (barrier skew + serial chain tails that
// cannot overlap across a barrier); work per phase is only ~800 cyc.
// Coarsening halves the fixed cost per tile without touching traffic,
// roles, or totals — isolates the barrier-count variable.
//
// P = 4-slot ring (slot = tile&3): consumer reads tiles 2S,2S+1 (slots
// {0,1} or {2,3}) while producers write 2S+2,2S+3 (the disjoint pair).
// K: 2 bufs/producer (even/odd tile), reload after last use (WAR ordering
// guarantees issue within the phase; consumed next phase ~4000 cyc later).
// V: 2 bufs/consumer (even/odd), same in-phase reload pattern.
// Producer w (w<4): kv-sub [16w,+16) of each tile, all 64 q-rows; swapped
// QK (r10/r11-verified): lane (qq,lw) holds S[kv=16w+4qq+i][q=16qt+lw],
// exp -> one b64 P-write per qt. Consumer w (w>=4): ch [64(w-4),+64),
// r0-proven af/V/PV patterns.
// ---------------------------------------------------------------------------
__global__ __launch_bounds__(512, 2) void flash_attn(
    const bf16* __restrict__ Qd, const bf16* __restrict__ Kd,
    const bf16* __restrict__ Vt, const float* __restrict__ x,
    const float* __restrict__ gamma, float* __restrict__ out) {
  __shared__ __align__(16) bf16 Pl[4][64 * 72];
  __shared__ float lsum[4][64];

  int tid = threadIdx.x;
  int lane = tid & 63, w = tid >> 6;
  int lw = lane & 15, qq = lane >> 4;
  int bb = blockIdx.y;
  int r0 = blockIdx.x * 64;

  const bf16* Qb = Qd + ((size_t)bb << 12) * 32;
  const bf16* Kb = Kd + ((size_t)bb << 12) * 32;
  const bf16* Vb = Vt + (size_t)bb * 256 * 4096;

  if (w < 4) {
    // ========================= PRODUCER =========================
    int kvs = 16 * w;
    bf16x8 qfp[4];
#pragma unroll
    for (int qt = 0; qt < 4; ++qt)
      qfp[qt] = *(const bf16x8*)(Qb + (size_t)(r0 + 16 * qt + lw) * 32 + qq * 8);
    float l_part[4] = {};
    bf16x8 kbA, kbB;   // kbA: even tiles, kbB: odd tiles

    // produce tile T from KREG into Pl[PS]
#define PROD_TILE(PS, KREG)                                                    \
    _Pragma("unroll") for (int qt = 0; qt < 4; ++qt) {                         \
      f32x4 z = {};                                                            \
      f32x4 s = mfma16(KREG, qfp[qt], z);                                      \
      bf16x4 pk;                                                               \
      _Pragma("unroll") for (int i = 0; i < 4; ++i) {                          \
        float p = __expf(s[i]); l_part[qt] += p; pk[i] = (bf16)p;              \
      }                                                                        \
      *(bf16x4*)&Pl[PS][(16 * qt + lw) * 72 + kvs + 4 * qq] = pk;              \
    }

    // ---- prologue: P(0)->slot0, P(1)->slot1; preload K(2),K(3) ----
    kbA = *(const bf16x8*)(Kb + (size_t)(kvs + lw) * 32 + qq * 8);
    kbB = *(const bf16x8*)(Kb + (size_t)(64 + kvs + lw) * 32 + qq * 8);
    PROD_TILE(0, kbA)
    PROD_TILE(1, kbB)
    kbA = *(const bf16x8*)(Kb + (size_t)(128 + kvs + lw) * 32 + qq * 8);
    kbB = *(const bf16x8*)(Kb + (size_t)(192 + kvs + lw) * 32 + qq * 8);
    wg_barrier();

    // super-phase S: produce tiles c0=2S+2 (slot WS0), c0+1 (WS1);
    // reload K((c0+2)&63)->kbA, K((c0+3)&63)->kbB.
#define PROD_SP(SS, WS0, WS1)                                                  \
    {                                                                          \
      const int c0 = 2 * (SS) + 2;                                             \
      if (c0 < 64) {                                                           \
        PROD_TILE(WS0, kbA)                                                    \
        kbA = *(const bf16x8*)(Kb + (size_t)((((c0 + 2) & 63) * 64) + kvs + lw) * 32 + qq * 8); \
        PROD_TILE(WS1, kbB)                                                    \
        kbB = *(const bf16x8*)(Kb + (size_t)((((c0 + 3) & 63) * 64) + kvs + lw) * 32 + qq * 8); \
      }                                                                        \
      wg_barrier();                                                            \
    }

    for (int jj = 0; jj < 16; ++jj) {
      PROD_SP(2 * jj,     2, 3)
      PROD_SP(2 * jj + 1, 0, 1)
    }
#undef PROD_SP
#undef PROD_TILE

#pragma unroll
    for (int qt = 0; qt < 4; ++qt) {
      float v = l_part[qt];
      v += __shfl_xor(v, 16);
      v += __shfl_xor(v, 32);
      if (qq == 0) lsum[w][16 * qt + lw] = v;
    }
    __syncthreads();
  } else {
    // ========================= CONSUMER =========================
    int chb = 64 * (w - 4);
    f32x4 o[4][4] = {};
    bf16x8 vA[8], vB[8];   // vA: even tiles, vB: odd tiles

    // consume tile (P slot PS, V regs VREGS), then reload VREGS from V(NV)
#define CONS_TILE(PS, VREGS, NV)                                               \
    {                                                                          \
      bf16x8 af[4][2];                                                         \
      _Pragma("unroll") for (int m = 0; m < 4; ++m)                            \
        _Pragma("unroll") for (int kc = 0; kc < 2; ++kc)                       \
          af[m][kc] = *(const bf16x8*)&Pl[PS][(16 * m + lw) * 72 + kc * 32 + qq * 8]; \
      _Pragma("unroll") for (int kc = 0; kc < 2; ++kc)                         \
        _Pragma("unroll") for (int t = 0; t < 4; ++t)                          \
          _Pragma("unroll") for (int m = 0; m < 4; ++m)                        \
            o[m][t] = mfma16(af[m][kc], VREGS[t * 2 + kc], o[m][t]);           \
      _Pragma("unroll") for (int t = 0; t < 4; ++t)                            \
        _Pragma("unroll") for (int kc = 0; kc < 2; ++kc)                       \
          VREGS[t * 2 + kc] = *(const bf16x8*)(Vb + (size_t)(chb + 16 * t + lw) * 4096 + (NV) + kc * 32 + qq * 8); \
    }

    // ---- prologue: load V(0)->vA, V(1)->vB ----
#pragma unroll
    for (int t = 0; t < 4; ++t)
#pragma unroll
      for (int kc = 0; kc < 2; ++kc) {
        vA[t * 2 + kc] = *(const bf16x8*)(Vb + (size_t)(chb + 16 * t + lw) * 4096 + kc * 32 + qq * 8);
        vB[t * 2 + kc] = *(const bf16x8*)(Vb + (size_t)(chb + 16 * t + lw) * 4096 + 64 + kc * 32 + qq * 8);
      }
    wg_barrier();

    // super-phase S: consume tiles c0=2S (slot RS0) with vA, c0+1 (RS1) with
    // vB; reload vA<-V((c0+2)&63), vB<-V((c0+3)&63) inside CONS_TILE.
#define CONS_SP(SS, RS0, RS1)                                                  \
    {                                                                          \
      const int c0 = 2 * (SS);                                                 \
      int nv0 = ((c0 + 2) & 63) * 64, nv1 = ((c0 + 3) & 63) * 64;              \
      CONS_TILE(RS0, vA, nv0)                                                  \
      CONS_TILE(RS1, vB, nv1)                                                  \
      wg_barrier();                                                            \
    }

    for (int jj = 0; jj < 16; ++jj) {
      CONS_SP(2 * jj,     0, 1)
      CONS_SP(2 * jj + 1, 2, 3)
    }
#undef CONS_SP
#undef CONS_TILE

    __syncthreads();   // producers' lsum now visible

    float g = gamma[0];
#pragma unroll
    for (int m = 0; m < 4; ++m) {
      f32x4 l0 = *(const f32x4*)&lsum[0][16 * m + 4 * qq];
      f32x4 l1 = *(const f32x4*)&lsum[1][16 * m + 4 * qq];
      f32x4 l2 = *(const f32x4*)&lsum[2][16 * m + 4 * qq];
      f32x4 l3 = *(const f32x4*)&lsum[3][16 * m + 4 * qq];
#pragma unroll
      for (int i = 0; i < 4; ++i) {
        float rinv = 1.f / (l0[i] + l1[i] + l2[i] + l3[i]);
        int row = r0 + 16 * m + 4 * qq + i;
        size_t base = (((size_t)bb << 12) + row) * 256 + chb;
#pragma unroll
        for (int t = 0; t < 4; ++t)
          out[base + 16 * t + lw] = g * (o[m][t][i] * rinv) + x[base + 16 * t + lw];
      }
    }
  }
}

extern "C" void kernel_launch(void* const* d_in, const int* in_sizes, int n_in,
                              void* d_out, int out_size, void* d_ws, size_t ws_size,
                              hipStream_t stream) {
  const float* x     = (const float*)d_in[0];
  const float* Wq    = (const float*)d_in[1];
  const float* bq    = (const float*)d_in[2];
  const float* Wk    = (const float*)d_in[3];
  const float* bk    = (const float*)d_in[4];
  const float* Wv    = (const float*)d_in[5];
  const float* bv    = (const float*)d_in[6];
  const float* gamma = (const float*)d_in[7];
  float* out = (float*)d_out;

  const size_t WT_E = 320 * 256;
  const size_t QK_E = (size_t)4096 * 32;
  const size_t VT_E = (size_t)256 * 4096;
  size_t full_bytes = (WT_E + 4 * 2 * QK_E + 4 * VT_E) * sizeof(bf16);

  bf16* Wf = (bf16*)d_ws;
  prep_wt<<<dim3(256), dim3(320), 0, stream>>>(Wq, Wk, Wv, Wf);

  if (ws_size >= full_bytes) {
    bf16* Qd = Wf + WT_E;
    bf16* Kd = Qd + 4 * QK_E;
    bf16* Vt = Kd + 4 * QK_E;
    qkv_gemm<<<dim3(256), dim3(256), 0, stream>>>(x, Wf, bq, bk, bv, Qd, Kd, Vt);
    flash_attn<<<dim3(64, 4), dim3(512), 0, stream>>>(Qd, Kd, Vt, x, gamma, out);
  } else {
    bf16* Qd = Wf + WT_E;
    bf16* Kd = Qd + QK_E;
    bf16* Vt = Kd + QK_E;
    for (int b = 0; b < 4; ++b) {
      const float* xb = x + (size_t)b * 4096 * 256;
      float* outb = out + (size_t)b * 4096 * 256;
      qkv_gemm<<<dim3(64), dim3(256), 0, stream>>>(xb, Wf, bq, bk, bv, Qd, Kd, Vt);
      flash_attn<<<dim3(64, 1), dim3(512), 0, stream>>>(Qd, Kd, Vt, xb, gamma, outb);
    }
  }
}